// Round 1
// baseline (249.025 us; speedup 1.0000x reference)
//
#include <hip/hip_runtime.h>

// out[b, i] = x[b, i] * kernel[i, i]
// B = 8192, N = 4096, fp32. Pure HBM-bandwidth problem: 128 MiB in + 128 MiB out.

#define DK_N 4096

// Step 1: gather the diagonal (4096 strided loads) into workspace so the main
// kernel reads it coalesced and L2-resident.
__global__ void dk_extract_diag(const float* __restrict__ k, float* __restrict__ d) {
    int i = blockIdx.x * blockDim.x + threadIdx.x;
    if (i < DK_N) d[i] = k[(size_t)i * (DK_N + 1)];
}

// Step 2: vectorized column-scale. One float4 per thread.
// N is divisible by 4, so float4 j covers columns 4c..4c+3 where c = j & (N/4 - 1).
__global__ __launch_bounds__(256) void dk_scale_cols(const float4* __restrict__ x,
                                                     const float4* __restrict__ diag4,
                                                     float4* __restrict__ out,
                                                     int n4) {
    int t = blockIdx.x * blockDim.x + threadIdx.x;
    if (t >= n4) return;
    float4 d = diag4[t & (DK_N / 4 - 1)];
    float4 v = x[t];
    v.x *= d.x;
    v.y *= d.y;
    v.z *= d.z;
    v.w *= d.w;
    out[t] = v;
}

extern "C" void kernel_launch(void* const* d_in, const int* in_sizes, int n_in,
                              void* d_out, int out_size, void* d_ws, size_t ws_size,
                              hipStream_t stream) {
    const float* x = (const float*)d_in[0];       // [B, N] fp32
    const float* kernel = (const float*)d_in[1];  // [N, N] fp32
    float* out = (float*)d_out;                   // [B, N] fp32
    float* diag = (float*)d_ws;                   // N floats of scratch

    // Extract diagonal.
    dk_extract_diag<<<(DK_N + 255) / 256, 256, 0, stream>>>(kernel, diag);

    // Scale: out_size = B*N elements, n4 float4s.
    int n4 = out_size / 4;
    int blocks = (n4 + 255) / 256;
    dk_scale_cols<<<blocks, 256, 0, stream>>>((const float4*)x,
                                              (const float4*)diag,
                                              (float4*)out, n4);
}

// Round 3
// 246.031 us; speedup vs baseline: 1.0122x; 1.0122x over previous
//
#include <hip/hip_runtime.h>

// out[b, i] = x[b, i] * kernel[i, i]
// B = 8192, N = 4096, fp32. Pure HBM-bandwidth problem: 128 MiB in + 128 MiB out.
// Floor at measured fill-rate (6.75 TB/s): ~40 us for the scale kernel.

#define DK_N 4096

// Native vector type: __builtin_nontemporal_* requires scalar/pointer/native-vector,
// not HIP's float4 class.
typedef float vfloat4 __attribute__((ext_vector_type(4)));

// Step 1: gather the diagonal (4096 strided loads) into workspace so the main
// kernel reads it coalesced and L1/L2-resident.
__global__ void dk_extract_diag(const float* __restrict__ k, float* __restrict__ d) {
    int i = blockIdx.x * blockDim.x + threadIdx.x;
    if (i < DK_N) d[i] = k[(size_t)i * (DK_N + 1)];
}

// Step 2: vectorized column-scale. One vfloat4 per thread.
// x/out are streamed once -> non-temporal (nt) to avoid L2 pollution.
// diag (16 KiB) is reused by every block -> normal cached load.
__global__ __launch_bounds__(256) void dk_scale_cols(const vfloat4* __restrict__ x,
                                                     const vfloat4* __restrict__ diag4,
                                                     vfloat4* __restrict__ out,
                                                     int n4) {
    int t = blockIdx.x * blockDim.x + threadIdx.x;
    if (t >= n4) return;
    vfloat4 d = diag4[t & (DK_N / 4 - 1)];
    vfloat4 v = __builtin_nontemporal_load(&x[t]);
    v *= d;
    __builtin_nontemporal_store(v, &out[t]);
}

extern "C" void kernel_launch(void* const* d_in, const int* in_sizes, int n_in,
                              void* d_out, int out_size, void* d_ws, size_t ws_size,
                              hipStream_t stream) {
    const float* x = (const float*)d_in[0];       // [B, N] fp32
    const float* kernel = (const float*)d_in[1];  // [N, N] fp32
    float* out = (float*)d_out;                   // [B, N] fp32
    float* diag = (float*)d_ws;                   // N floats of scratch

    dk_extract_diag<<<(DK_N + 255) / 256, 256, 0, stream>>>(kernel, diag);

    int n4 = out_size / 4;  // B*N/4 vfloat4s
    int blocks = (n4 + 255) / 256;
    dk_scale_cols<<<blocks, 256, 0, stream>>>((const vfloat4*)x,
                                              (const vfloat4*)diag,
                                              (vfloat4*)out, n4);
}